// Round 12
// baseline (165.713 us; speedup 1.0000x reference)
//
#include <hip/hip_runtime.h>

// Problem constants
constexpr int N = 4096, E = 131072, OUTF = 86, NB = 16, HEADS = 4, DH = 16;
constexpr int CAP = 128;   // padded bucket capacity per node (mean deg = 32)
constexpr int NSPLIT = 8, KEYS = N / NSPLIT;  // 512 keys per attention split
constexpr int PCKS = 8;    // u64 stride per node in pck (64 B line per node)

typedef __attribute__((ext_vector_type(8))) short short8;
typedef __attribute__((ext_vector_type(4))) float f32x4;

constexpr unsigned long long PK_MASK = (1ULL << 40) - 1;  // low 40: fixed-point deg
constexpr float PK_SCALE = 1.0f / 16777216.0f;            // 2^-24

// Workspace offsets (float units, 16B-aligned)
constexpr size_t OFF_PCK   = 0;                           // N*PCKS u64 = 16N words
constexpr size_t OFF_WC    = OFF_PCK + 16 * (size_t)N;    // [16][N] pooling coeffs (zeroed w/ pck)
constexpr size_t OFF_INV   = OFF_WC + 16 * (size_t)N;     // 16
constexpr size_t OFF_BUFA  = OFF_INV + 16;                // N*64 (xW1)
constexpr size_t OFF_QP    = OFF_BUFA + (size_t)N * 64;   // HEADS*N*16 bf16 = N*32 floats
constexpr size_t OFF_KP    = OFF_QP + (size_t)N * 32;
constexpr size_t OFF_VP    = OFF_KP + (size_t)N * 32;     // [h][16][N] bf16
constexpr size_t OFF_EPAIR = OFF_VP + (size_t)N * 32;     // N*CAP int2 {src, w}
constexpr size_t OFF_OPART = OFF_EPAIR + (size_t)2 * N * CAP;  // HEADS*N*NSPLIT*16
constexpr size_t OFF_LPART = OFF_OPART + (size_t)HEADS * N * NSPLIT * 16;  // HEADS*N*NSPLIT
constexpr size_t OFF_UPART = OFF_LPART + (size_t)HEADS * N * NSPLIT;       // 256*16*64

__device__ inline unsigned short f2bf(float f) {  // RNE float->bf16
    unsigned u = __builtin_bit_cast(unsigned, f);
    u += 0x7FFFu + ((u >> 16) & 1u);
    return (unsigned short)(u >> 16);
}

__device__ inline float pk_deg(unsigned long long pk) {   // decode weighted degree
    return (float)(pk & PK_MASK) * PK_SCALE;
}

// ===== D1: gemm1 (blk<256) || edge bucket fill x4 (256..383) || invcnt (384) =====
__global__ __launch_bounds__(256) void d1_kernel(const float* __restrict__ x,
        const float* __restrict__ W1, const int* __restrict__ ei,
        const float* __restrict__ ea, const int* __restrict__ batch,
        float* __restrict__ ws) {
    __shared__ float4 Ws4[64 * 17];
    __shared__ float4 As4[16 * 17];
    __shared__ int bnd[NB + 1];
    int blk = blockIdx.x, tid = threadIdx.x;
    if (blk < 256) {
        float* bufA = ws + OFF_BUFA;
        for (int idx = tid; idx < 64 * 16; idx += 256)
            Ws4[(idx >> 4) * 17 + (idx & 15)] = ((const float4*)W1)[idx];
        {
            int r = tid >> 4, k4 = tid & 15;
            As4[r * 17 + k4] = ((const float4*)x)[(size_t)(blk * 16 + r) * 16 + k4];
        }
        __syncthreads();
        int r2 = tid & 7, cg = tid >> 3;
        float acc[2][2] = {};
#pragma unroll
        for (int k4 = 0; k4 < 16; ++k4) {
            float4 a0 = As4[r2 * 17 + k4], a1 = As4[(r2 + 8) * 17 + k4];
#pragma unroll
            for (int i = 0; i < 2; ++i) {
                float4 w = Ws4[(cg + 32 * i) * 17 + k4];
                acc[0][i] += a0.x * w.x + a0.y * w.y + a0.z * w.z + a0.w * w.w;
                acc[1][i] += a1.x * w.x + a1.y * w.y + a1.z * w.z + a1.w * w.w;
            }
        }
#pragma unroll
        for (int j = 0; j < 2; ++j)
#pragma unroll
            for (int i = 0; i < 2; ++i)
                bufA[(size_t)(blk * 16 + r2 + 8 * j) * 64 + cg + 32 * i] = acc[j][i];
    } else if (blk < 384) {
        unsigned long long* pck = (unsigned long long*)(ws + OFF_PCK);
        int2* epair = (int2*)(ws + OFF_EPAIR);
        int f = (blk - 256) * 256 + tid;          // [0, E/4)
        int e[4] = { f, f + E / 4, f + E / 2, f + 3 * (E / 4) };
        int s[4], d[4]; float w[4];
#pragma unroll
        for (int i = 0; i < 4; ++i) { s[i] = ei[e[i]]; d[i] = ei[E + e[i]]; w[i] = ea[e[i]]; }
        unsigned long long o[4];
#pragma unroll
        for (int i = 0; i < 4; ++i) {
            unsigned long long a = (1ULL << 40)
                + (unsigned long long)(unsigned)(w[i] * 16777216.0f + 0.5f);
            o[i] = atomicAdd(&pck[(size_t)d[i] * PCKS], a);  // 4 independent round-trips
        }
#pragma unroll
        for (int i = 0; i < 4; ++i) {
            int p = (int)(o[i] >> 40);
            if (p < CAP) epair[(size_t)d[i] * CAP + p] = make_int2(s[i], __float_as_int(w[i]));
        }
    } else {
        // 17 parallel binary searches -> invcnt
        float* invcnt = ws + OFF_INV;
        if (tid <= NB) {
            int b = tid, lo = 0, hi = N;
            while (lo < hi) { int m = (lo + hi) >> 1; if (batch[m] < b) lo = m + 1; else hi = m; }
            bnd[tid] = lo;
        }
        __syncthreads();
        if (tid < NB) {
            int cnt = bnd[tid + 1] - bnd[tid];
            invcnt[tid] = cnt > 0 ? 1.0f / (float)cnt : 0.0f;
        }
    }
}

// ===== D23: fused agg1(+b1,ReLU in LDS) -> QKV gemm + bf16 pack; scatters Wc =====
// block = 1024 threads = 16 waves = 16 nodes.
__global__ __launch_bounds__(1024) void d23_kernel(const float* __restrict__ Win,
        const float* __restrict__ b1, const float* __restrict__ b_in,
        const int* __restrict__ batch, float* __restrict__ ws) {
    __shared__ float4 Ws4[16 * 200];   // [k4][c] (c<192, pad 200): reads lane-consecutive
    __shared__ float  Af[16 * 68];     // h1 rows (stride 68 floats = 17 float4)

    const unsigned long long* pck = (const unsigned long long*)(ws + OFF_PCK);
    const int2*  epair = (const int2*)(ws + OFF_EPAIR);
    float*       Wc    = ws + OFF_WC;          // [16][N]
    const float* invcnt= ws + OFF_INV;
    const float* bufA  = ws + OFF_BUFA;
    unsigned short* Qp = (unsigned short*)(ws + OFF_QP);
    unsigned short* Kp = (unsigned short*)(ws + OFF_KP);
    unsigned short* Vp = (unsigned short*)(ws + OFF_VP);

    const int tid = threadIdx.x, lane = tid & 63, wv = tid >> 6;
    for (int idx = tid; idx < 192 * 16; idx += 1024) {
        int c = idx >> 4, k4 = idx & 15;
        Ws4[k4 * 200 + c] = ((const float4*)Win)[idx];
    }

    // phase 1: wave wv aggregates node; scatters pooling coeffs Wc[batch(node)][src]
    const int node = blockIdx.x * 16 + wv;
    {
        const unsigned long long pkn = pck[(size_t)node * PCKS];
        const float di = rsqrtf(pk_deg(pkn) + 1.0f);   // self-loop: deg+1
        const int bb = batch[node];
        const float invb = invcnt[bb];
        float* Wcb = Wc + (size_t)bb * N;
        float acc0 = (di * di) * bufA[(size_t)node * 64 + lane];
        float acc1 = 0.f, acc2 = 0.f, acc3 = 0.f;
        if (lane == 0) atomicAdd(&Wcb[node], di * di * invb);  // self-loop pool coeff
        const int cnt = min((int)(pkn >> 40), CAP);
        const int2* pe = epair + (size_t)node * CAP;
        for (int base = 0; base < cnt; base += 64) {
            int rem = cnt - base;
            int   sl = 0;
            float nl = 0.f;
            if (lane < rem) {                      // coalesced 8B load per lane
                int2 e = pe[base + lane];
                sl = e.x;
                float w = __int_as_float(e.y);
                nl = rsqrtf(pk_deg(pck[(size_t)sl * PCKS]) + 1.0f) * w * di;
                atomicAdd(&Wcb[sl], nl * invb);    // pooling coeff (fire-and-forget)
            }
            int m = rem < 64 ? rem : 64;
            int j = 0;
            for (; j + 4 <= m; j += 4) {           // 4 row-gathers in flight
                int   s0 = __shfl(sl, j),     s1 = __shfl(sl, j + 1);
                int   s2 = __shfl(sl, j + 2), s3 = __shfl(sl, j + 3);
                float n0 = __shfl(nl, j),     n1 = __shfl(nl, j + 1);
                float n2 = __shfl(nl, j + 2), n3 = __shfl(nl, j + 3);
                acc0 += n0 * bufA[(size_t)s0 * 64 + lane];
                acc1 += n1 * bufA[(size_t)s1 * 64 + lane];
                acc2 += n2 * bufA[(size_t)s2 * 64 + lane];
                acc3 += n3 * bufA[(size_t)s3 * 64 + lane];
            }
            for (; j < m; ++j) {
                int   s0 = __shfl(sl, j);
                float n0 = __shfl(nl, j);
                acc0 += n0 * bufA[(size_t)s0 * 64 + lane];
            }
        }
        Af[wv * 68 + lane] = fmaxf((acc0 + acc1) + (acc2 + acc3) + b1[lane], 0.0f);
    }
    __syncthreads();

    // phase 2: wave wv computes QKV row (node); lane handles cols {lane, lane+64, lane+128}
    {
        const float4* Af4 = (const float4*)Af;
        float acc[3];
#pragma unroll
        for (int i = 0; i < 3; ++i) acc[i] = b_in[lane + 64 * i];
#pragma unroll
        for (int k4 = 0; k4 < 16; ++k4) {
            float4 a = Af4[wv * 17 + k4];          // wave-broadcast
#pragma unroll
            for (int i = 0; i < 3; ++i) {
                float4 w = Ws4[k4 * 200 + lane + 64 * i];  // lane-consecutive
                acc[i] += a.x * w.x + a.y * w.y + a.z * w.z + a.w * w.w;
            }
        }
        const int row = node;
#pragma unroll
        for (int i = 0; i < 3; ++i) {
            int c = lane + 64 * i;
            float v = acc[i];
            if (c < 64) {
                int h = c >> 4, d = c & 15;
                Qp[((size_t)h * N + row) * 16 + d] = f2bf(v * 0.25f);  // 1/sqrt(DH)
            } else if (c < 128) {
                int c2 = c - 64, h = c2 >> 4, d = c2 & 15;
                Kp[((size_t)h * N + row) * 16 + d] = f2bf(v);
            } else {
                int c2 = c - 128, h = c2 >> 4, d = c2 & 15;
                Vp[((size_t)h * 16 + d) * N + row] = f2bf(v);
            }
        }
    }
}

// ===== attn: MFMA flash attention, KV-split (proven) =====
__global__ __launch_bounds__(256) void attn_kernel(const float* __restrict__ ws_c,
        float* __restrict__ ws) {
    __shared__ __align__(16) unsigned short Plds[4 * 640];  // per-wave P roundtrip

    const unsigned short* Qp = (const unsigned short*)(ws_c + OFF_QP);
    const unsigned short* Kp = (const unsigned short*)(ws_c + OFF_KP);
    const unsigned short* Vp = (const unsigned short*)(ws_c + OFF_VP);
    float* opart = ws + OFF_OPART;
    float* lpart = ws + OFF_LPART;

    const int h  = blockIdx.y;
    const int sp = blockIdx.z;
    const int k0 = sp * KEYS;
    const int tid = threadIdx.x;
    const int lane = tid & 63, wv = tid >> 6;
    const int q15 = lane & 15, quad = lane >> 4;

    const int qbase = blockIdx.x * 64 + wv * 16;
    short8 qf = {};
    if (quad < 2)
        qf = *(const short8*)&Qp[((size_t)h * N + qbase + q15) * 16 + quad * 8];

    f32x4 O = {0.f, 0.f, 0.f, 0.f};
    float l = 0.f;
    unsigned short* Pw = &Plds[wv * 640];
    const unsigned short* Kh = Kp + (size_t)h * N * 16;
    const unsigned short* Vh = Vp + ((size_t)h * 16 + q15) * N + k0;

#pragma unroll 2
    for (int ch = 0; ch < KEYS / 32; ++ch) {
#pragma unroll
        for (int t = 0; t < 2; ++t) {
            short8 kf = {};
            if (quad < 2)
                kf = *(const short8*)&Kh[(size_t)(k0 + ch * 32 + t * 16 + q15) * 16 + quad * 8];
            f32x4 zero = {0.f, 0.f, 0.f, 0.f};
            f32x4 s = __builtin_amdgcn_mfma_f32_16x16x32_bf16(kf, qf, zero, 0, 0, 0);
            // C-layout: col=query=lane&15, row=key=quad*4+reg
            float p0 = __expf(s[0]), p1 = __expf(s[1]), p2 = __expf(s[2]), p3 = __expf(s[3]);
            l += p0 + p1 + p2 + p3;
            ushort4 pu;
            pu.x = f2bf(p0); pu.y = f2bf(p1); pu.z = f2bf(p2); pu.w = f2bf(p3);
            *(ushort4*)&Pw[q15 * 40 + t * 16 + quad * 4] = pu;
        }
        asm volatile("s_waitcnt lgkmcnt(0)" ::: "memory");
        short8 pf = *(const short8*)&Pw[q15 * 40 + quad * 8];   // A: m=query, k=key
        short8 vf = *(const short8*)&Vh[ch * 32 + quad * 8];    // B: n=dh,    k=key
        O = __builtin_amdgcn_mfma_f32_16x16x32_bf16(pf, vf, O, 0, 0, 0);
    }

    l += __shfl_xor(l, 16);
    l += __shfl_xor(l, 32);
    if (lane < 16)
        lpart[((size_t)h * N + qbase + q15) * NSPLIT + sp] = l;
#pragma unroll
    for (int r = 0; r < 4; ++r) {
        int query = qbase + quad * 4 + r;
        opart[(((size_t)h * N + query) * NSPLIT + sp) * 16 + q15] = O[r];
    }
}

// ===== D4b: combine splits -> Wc-weighted partial pool (no GEMMs, no atomics) =====
__global__ __launch_bounds__(256) void d4b_kernel(float* __restrict__ ws) {
    __shared__ float o_sh[16 * 68];
    __shared__ float Wc_sh[16][17];

    const float* opart = ws + OFF_OPART;
    const float* lpart = ws + OFF_LPART;
    const float* Wc    = ws + OFF_WC;   // [16][N]
    float*       Upart = ws + OFF_UPART;

    const int tid = threadIdx.x, qbase = blockIdx.x * 16;
    // combine: o_sh[r][f] = sum_s opart / sum_s lpart
    for (int idx = tid; idx < 16 * 64; idx += 256) {
        int r = idx >> 6, f = idx & 63;
        int h = f >> 4, d = f & 15;
        size_t base = ((size_t)h * N + qbase + r) * NSPLIT;
        float L = 0.f, acc = 0.f;
#pragma unroll
        for (int s = 0; s < NSPLIT; ++s) {
            L += lpart[base + s];
            acc += opart[(base + s) * 16 + d];
        }
        o_sh[r * 68 + f] = acc / L;
    }
    {
        int j = tid & 15, g = tid >> 4;   // contiguous 16-float reads per graph row
        Wc_sh[j][g] = Wc[(size_t)g * N + qbase + j];
    }
    __syncthreads();
    // Up[g][f] = sum_j Wc[g][qbase+j] * o[j][f]; thread = (g, f-quad)
    int g = tid >> 4, fq = tid & 15;
    float4 acc = {0.f, 0.f, 0.f, 0.f};
#pragma unroll
    for (int j = 0; j < 16; ++j) {
        float w = Wc_sh[j][g];
        const float* orow = &o_sh[j * 68 + fq * 4];
        acc.x += w * orow[0]; acc.y += w * orow[1];
        acc.z += w * orow[2]; acc.w += w * orow[3];
    }
    *(float4*)&Upart[(((size_t)blockIdx.x) * 16 + g) * 64 + fq * 4] = acc;
}

// ===== D6: reduce Upart -> U; s = rowsum(Wc); out = (U@Wout^T + s*b_out)@W2^T + b2 =====
__global__ __launch_bounds__(256) void d6_kernel(const float* __restrict__ Wout,
        const float* __restrict__ b_out, const float* __restrict__ W2,
        const float* __restrict__ b2, const float* __restrict__ ws,
        float* __restrict__ out) {
    __shared__ float red[4][64];
    __shared__ float s_red[4];
    __shared__ float U_sh[64], V_sh[64];

    const float* Upart = ws + OFF_UPART;
    const float* Wc    = ws + OFF_WC;    // [16][N]
    const float* invcnt= ws + OFF_INV;

    const int b = blockIdx.x, tid = threadIdx.x, lane = tid & 63, wv = tid >> 6;
    float acc = 0.f;
    for (int blk = wv; blk < 256; blk += 4)
        acc += Upart[((size_t)blk * 16 + b) * 64 + lane];
    red[wv][lane] = acc;
    float sacc = 0.f;
    for (int j = tid; j < N; j += 256) sacc += Wc[(size_t)b * N + j];
#pragma unroll
    for (int off = 1; off < 64; off <<= 1) sacc += __shfl_xor(sacc, off);
    if (lane == 0) s_red[wv] = sacc;
    __syncthreads();
    if (wv == 0)
        U_sh[lane] = (red[0][lane] + red[1][lane]) + (red[2][lane] + red[3][lane]);
    __syncthreads();
    const float s = (s_red[0] + s_red[1]) + (s_red[2] + s_red[3]);
    if (tid < 64) {
        float v = s * b_out[tid];
#pragma unroll 8
        for (int k = 0; k < 64; ++k) v += U_sh[k] * Wout[tid * 64 + k];
        V_sh[tid] = v;
    }
    __syncthreads();
    if (tid < OUTF) {
        float o = b2[tid];
#pragma unroll 8
        for (int f = 0; f < 64; ++f) o += V_sh[f] * W2[tid * 64 + f];
        out[b * OUTF + tid] = invcnt[b] > 0.f ? o : 0.0f;
    }
}

extern "C" void kernel_launch(void* const* d_in, const int* in_sizes, int n_in,
                              void* d_out, int out_size, void* d_ws, size_t ws_size,
                              hipStream_t stream) {
    const float* x     = (const float*)d_in[0];
    const int*   ei    = (const int*)  d_in[1];
    const float* ea    = (const float*)d_in[2];
    const int*   batch = (const int*)  d_in[3];
    const float* W1    = (const float*)d_in[4];
    const float* b1    = (const float*)d_in[5];
    const float* Win   = (const float*)d_in[6];
    const float* b_in  = (const float*)d_in[7];
    const float* Wout  = (const float*)d_in[8];
    const float* b_out = (const float*)d_in[9];
    const float* W2    = (const float*)d_in[10];
    const float* b2    = (const float*)d_in[11];
    float* out = (float*)d_out;
    float* ws  = (float*)d_ws;

    // zero pck (16N) + Wc (16N) in one contiguous memset (512 KB)
    hipMemsetAsync(ws + OFF_PCK, 0, (size_t)32 * N * 4, stream);
    d1_kernel<<<385, 256, 0, stream>>>(x, W1, ei, ea, batch, ws);
    d23_kernel<<<N / 16, 1024, 0, stream>>>(Win, b1, b_in, batch, ws);
    attn_kernel<<<dim3(N / 64, HEADS, NSPLIT), 256, 0, stream>>>(ws, ws);
    d4b_kernel<<<N / 16, 256, 0, stream>>>(ws);
    d6_kernel<<<NB, 256, 0, stream>>>(Wout, b_out, W2, b2, ws, out);
}

// Round 13
// 165.648 us; speedup vs baseline: 1.0004x; 1.0004x over previous
//
#include <hip/hip_runtime.h>

// Problem constants
constexpr int N = 4096, E = 131072, OUTF = 86, NB = 16, HEADS = 4, DH = 16;
constexpr int CAP = 128;   // padded bucket capacity per node (mean deg = 32)
constexpr int NSPLIT = 8, KEYS = N / NSPLIT;  // 512 keys per attention split
constexpr int PCKS = 8;    // u64 stride per node in pck (64 B line per node)

typedef __attribute__((ext_vector_type(8))) short short8;
typedef __attribute__((ext_vector_type(4))) float f32x4;

constexpr unsigned long long PK_MASK = (1ULL << 40) - 1;  // low 40: fixed-point deg
constexpr float PK_SCALE = 1.0f / 16777216.0f;            // 2^-24

// Workspace offsets (float units, 16B-aligned)
constexpr size_t OFF_PCK   = 0;                           // N*PCKS u64 = 16N words
constexpr size_t OFF_WC    = OFF_PCK + 16 * (size_t)N;    // [16][N] pooling coeffs (zeroed w/ pck)
constexpr size_t OFF_INV   = OFF_WC + 16 * (size_t)N;     // 16
constexpr size_t OFF_BUFA  = OFF_INV + 16;                // N*64 (xW1)
constexpr size_t OFF_QP    = OFF_BUFA + (size_t)N * 64;   // HEADS*N*16 bf16 = N*32 floats
constexpr size_t OFF_KP    = OFF_QP + (size_t)N * 32;
constexpr size_t OFF_VP    = OFF_KP + (size_t)N * 32;     // [h][16][N] bf16
constexpr size_t OFF_EPAIR = OFF_VP + (size_t)N * 32;     // N*CAP int2 {src, w}
constexpr size_t OFF_OPART = OFF_EPAIR + (size_t)2 * N * CAP;  // HEADS*N*NSPLIT*16
constexpr size_t OFF_LPART = OFF_OPART + (size_t)HEADS * N * NSPLIT * 16;  // HEADS*N*NSPLIT
constexpr size_t OFF_UPART = OFF_LPART + (size_t)HEADS * N * NSPLIT;       // 256*16*64

__device__ inline unsigned short f2bf(float f) {  // RNE float->bf16
    unsigned u = __builtin_bit_cast(unsigned, f);
    u += 0x7FFFu + ((u >> 16) & 1u);
    return (unsigned short)(u >> 16);
}

__device__ inline float pk_deg(unsigned long long pk) {   // decode weighted degree
    return (float)(pk & PK_MASK) * PK_SCALE;
}

// ===== D1: gemm1 (blk<256) || edge bucket fill x2 (256..511) || invcnt (512) =====
__global__ __launch_bounds__(256) void d1_kernel(const float* __restrict__ x,
        const float* __restrict__ W1, const int* __restrict__ ei,
        const float* __restrict__ ea, const int* __restrict__ batch,
        float* __restrict__ ws) {
    __shared__ float4 Ws4[64 * 17];
    __shared__ float4 As4[16 * 17];
    __shared__ int bnd[NB + 1];
    int blk = blockIdx.x, tid = threadIdx.x;
    if (blk < 256) {
        float* bufA = ws + OFF_BUFA;
        for (int idx = tid; idx < 64 * 16; idx += 256)
            Ws4[(idx >> 4) * 17 + (idx & 15)] = ((const float4*)W1)[idx];
        {
            int r = tid >> 4, k4 = tid & 15;
            As4[r * 17 + k4] = ((const float4*)x)[(size_t)(blk * 16 + r) * 16 + k4];
        }
        __syncthreads();
        int r2 = tid & 7, cg = tid >> 3;
        float acc[2][2] = {};
#pragma unroll
        for (int k4 = 0; k4 < 16; ++k4) {
            float4 a0 = As4[r2 * 17 + k4], a1 = As4[(r2 + 8) * 17 + k4];
#pragma unroll
            for (int i = 0; i < 2; ++i) {
                float4 w = Ws4[(cg + 32 * i) * 17 + k4];
                acc[0][i] += a0.x * w.x + a0.y * w.y + a0.z * w.z + a0.w * w.w;
                acc[1][i] += a1.x * w.x + a1.y * w.y + a1.z * w.z + a1.w * w.w;
            }
        }
#pragma unroll
        for (int j = 0; j < 2; ++j)
#pragma unroll
            for (int i = 0; i < 2; ++i)
                bufA[(size_t)(blk * 16 + r2 + 8 * j) * 64 + cg + 32 * i] = acc[j][i];
    } else if (blk < 512) {
        unsigned long long* pck = (unsigned long long*)(ws + OFF_PCK);
        int2* epair = (int2*)(ws + OFF_EPAIR);
        int f = (blk - 256) * 256 + tid;          // [0, E/2)
        int e0 = f, e1 = f + E / 2;
        int s0 = ei[e0], d0 = ei[E + e0];
        int s1 = ei[e1], d1 = ei[E + e1];
        float w0 = ea[e0], w1 = ea[e1];
        unsigned long long a0 = (1ULL << 40) + (unsigned long long)(unsigned)(w0 * 16777216.0f + 0.5f);
        unsigned long long a1 = (1ULL << 40) + (unsigned long long)(unsigned)(w1 * 16777216.0f + 0.5f);
        unsigned long long o0 = atomicAdd(&pck[(size_t)d0 * PCKS], a0);
        unsigned long long o1 = atomicAdd(&pck[(size_t)d1 * PCKS], a1);
        int p0 = (int)(o0 >> 40), p1 = (int)(o1 >> 40);
        if (p0 < CAP) epair[(size_t)d0 * CAP + p0] = make_int2(s0, __float_as_int(w0));
        if (p1 < CAP) epair[(size_t)d1 * CAP + p1] = make_int2(s1, __float_as_int(w1));
    } else {
        // 17 parallel binary searches -> invcnt
        float* invcnt = ws + OFF_INV;
        if (tid <= NB) {
            int b = tid, lo = 0, hi = N;
            while (lo < hi) { int m = (lo + hi) >> 1; if (batch[m] < b) lo = m + 1; else hi = m; }
            bnd[tid] = lo;
        }
        __syncthreads();
        if (tid < NB) {
            int cnt = bnd[tid + 1] - bnd[tid];
            invcnt[tid] = cnt > 0 ? 1.0f / (float)cnt : 0.0f;
        }
    }
}

// ===== D23: fused agg1(+b1,ReLU in LDS) -> QKV gemm + bf16 pack =====
// Wc pooling-coeff atomics DEFERRED to kernel tail (post-barrier) so the
// __syncthreads vmcnt(0) drain doesn't serialize on random scatter atomics.
__global__ __launch_bounds__(1024) void d23_kernel(const float* __restrict__ Win,
        const float* __restrict__ b1, const float* __restrict__ b_in,
        const int* __restrict__ batch, float* __restrict__ ws) {
    __shared__ float4 Ws4[16 * 200];   // [k4][c] (c<192, pad 200): reads lane-consecutive
    __shared__ float  Af[16 * 68];     // h1 rows (stride 68 floats = 17 float4)

    const unsigned long long* pck = (const unsigned long long*)(ws + OFF_PCK);
    const int2*  epair = (const int2*)(ws + OFF_EPAIR);
    float*       Wc    = ws + OFF_WC;          // [16][N]
    const float* invcnt= ws + OFF_INV;
    const float* bufA  = ws + OFF_BUFA;
    unsigned short* Qp = (unsigned short*)(ws + OFF_QP);
    unsigned short* Kp = (unsigned short*)(ws + OFF_KP);
    unsigned short* Vp = (unsigned short*)(ws + OFF_VP);

    const int tid = threadIdx.x, lane = tid & 63, wv = tid >> 6;
    for (int idx = tid; idx < 192 * 16; idx += 1024) {
        int c = idx >> 4, k4 = idx & 15;
        Ws4[k4 * 200 + c] = ((const float4*)Win)[idx];
    }

    // phase 1: wave wv aggregates node; records (src, coeff) in regs for tail scatter
    const int node = blockIdx.x * 16 + wv;
    int   sl0 = 0, sl1 = 0;
    float cv0 = 0.f, cv1 = 0.f;       // nl * invb, valid iff flags below
    bool  v0 = false, v1 = false;
    float self_c;
    float* Wcb;
    {
        const unsigned long long pkn = pck[(size_t)node * PCKS];
        const float di = rsqrtf(pk_deg(pkn) + 1.0f);   // self-loop: deg+1
        const int bb = batch[node];
        const float invb = invcnt[bb];
        Wcb = Wc + (size_t)bb * N;
        self_c = di * di * invb;
        float acc0 = (di * di) * bufA[(size_t)node * 64 + lane];
        float acc1 = 0.f, acc2 = 0.f, acc3 = 0.f;
        const int cnt = min((int)(pkn >> 40), CAP);
        const int2* pe = epair + (size_t)node * CAP;
        for (int base = 0; base < cnt; base += 64) {
            int rem = cnt - base;
            int   sl = 0;
            float nl = 0.f;
            if (lane < rem) {                      // coalesced 8B load per lane
                int2 e = pe[base + lane];
                sl = e.x;
                float w = __int_as_float(e.y);
                nl = rsqrtf(pk_deg(pck[(size_t)sl * PCKS]) + 1.0f) * w * di;
                if (base == 0) { sl0 = sl; cv0 = nl * invb; v0 = true; }
                else           { sl1 = sl; cv1 = nl * invb; v1 = true; }
            }
            int m = rem < 64 ? rem : 64;
            int j = 0;
            for (; j + 4 <= m; j += 4) {           // 4 row-gathers in flight
                int   s0 = __shfl(sl, j),     s1 = __shfl(sl, j + 1);
                int   s2 = __shfl(sl, j + 2), s3 = __shfl(sl, j + 3);
                float n0 = __shfl(nl, j),     n1 = __shfl(nl, j + 1);
                float n2 = __shfl(nl, j + 2), n3 = __shfl(nl, j + 3);
                acc0 += n0 * bufA[(size_t)s0 * 64 + lane];
                acc1 += n1 * bufA[(size_t)s1 * 64 + lane];
                acc2 += n2 * bufA[(size_t)s2 * 64 + lane];
                acc3 += n3 * bufA[(size_t)s3 * 64 + lane];
            }
            for (; j < m; ++j) {
                int   s0 = __shfl(sl, j);
                float n0 = __shfl(nl, j);
                acc0 += n0 * bufA[(size_t)s0 * 64 + lane];
            }
        }
        Af[wv * 68 + lane] = fmaxf((acc0 + acc1) + (acc2 + acc3) + b1[lane], 0.0f);
    }
    __syncthreads();

    // phase 2: wave wv computes QKV row (node); lane handles cols {lane, lane+64, lane+128}
    {
        const float4* Af4 = (const float4*)Af;
        float acc[3];
#pragma unroll
        for (int i = 0; i < 3; ++i) acc[i] = b_in[lane + 64 * i];
#pragma unroll
        for (int k4 = 0; k4 < 16; ++k4) {
            float4 a = Af4[wv * 17 + k4];          // wave-broadcast
#pragma unroll
            for (int i = 0; i < 3; ++i) {
                float4 w = Ws4[k4 * 200 + lane + 64 * i];  // lane-consecutive
                acc[i] += a.x * w.x + a.y * w.y + a.z * w.z + a.w * w.w;
            }
        }
        const int row = node;
#pragma unroll
        for (int i = 0; i < 3; ++i) {
            int c = lane + 64 * i;
            float v = acc[i];
            if (c < 64) {
                int h = c >> 4, d = c & 15;
                Qp[((size_t)h * N + row) * 16 + d] = f2bf(v * 0.25f);  // 1/sqrt(DH)
            } else if (c < 128) {
                int c2 = c - 64, h = c2 >> 4, d = c2 & 15;
                Kp[((size_t)h * N + row) * 16 + d] = f2bf(v);
            } else {
                int c2 = c - 128, h = c2 >> 4, d = c2 & 15;
                Vp[((size_t)h * 16 + d) * N + row] = f2bf(v);
            }
        }
    }

    // tail: Wc pooling-coeff scatter (fire-and-forget; drain overlaps across blocks)
    if (lane == 0) atomicAdd(&Wcb[node], self_c);
    if (v0) atomicAdd(&Wcb[sl0], cv0);
    if (v1) atomicAdd(&Wcb[sl1], cv1);
}

// ===== attn: MFMA flash attention, KV-split (proven) =====
__global__ __launch_bounds__(256) void attn_kernel(const float* __restrict__ ws_c,
        float* __restrict__ ws) {
    __shared__ __align__(16) unsigned short Plds[4 * 640];  // per-wave P roundtrip

    const unsigned short* Qp = (const unsigned short*)(ws_c + OFF_QP);
    const unsigned short* Kp = (const unsigned short*)(ws_c + OFF_KP);
    const unsigned short* Vp = (const unsigned short*)(ws_c + OFF_VP);
    float* opart = ws + OFF_OPART;
    float* lpart = ws + OFF_LPART;

    const int h  = blockIdx.y;
    const int sp = blockIdx.z;
    const int k0 = sp * KEYS;
    const int tid = threadIdx.x;
    const int lane = tid & 63, wv = tid >> 6;
    const int q15 = lane & 15, quad = lane >> 4;

    const int qbase = blockIdx.x * 64 + wv * 16;
    short8 qf = {};
    if (quad < 2)
        qf = *(const short8*)&Qp[((size_t)h * N + qbase + q15) * 16 + quad * 8];

    f32x4 O = {0.f, 0.f, 0.f, 0.f};
    float l = 0.f;
    unsigned short* Pw = &Plds[wv * 640];
    const unsigned short* Kh = Kp + (size_t)h * N * 16;
    const unsigned short* Vh = Vp + ((size_t)h * 16 + q15) * N + k0;

#pragma unroll 2
    for (int ch = 0; ch < KEYS / 32; ++ch) {
#pragma unroll
        for (int t = 0; t < 2; ++t) {
            short8 kf = {};
            if (quad < 2)
                kf = *(const short8*)&Kh[(size_t)(k0 + ch * 32 + t * 16 + q15) * 16 + quad * 8];
            f32x4 zero = {0.f, 0.f, 0.f, 0.f};
            f32x4 s = __builtin_amdgcn_mfma_f32_16x16x32_bf16(kf, qf, zero, 0, 0, 0);
            // C-layout: col=query=lane&15, row=key=quad*4+reg
            float p0 = __expf(s[0]), p1 = __expf(s[1]), p2 = __expf(s[2]), p3 = __expf(s[3]);
            l += p0 + p1 + p2 + p3;
            ushort4 pu;
            pu.x = f2bf(p0); pu.y = f2bf(p1); pu.z = f2bf(p2); pu.w = f2bf(p3);
            *(ushort4*)&Pw[q15 * 40 + t * 16 + quad * 4] = pu;
        }
        asm volatile("s_waitcnt lgkmcnt(0)" ::: "memory");
        short8 pf = *(const short8*)&Pw[q15 * 40 + quad * 8];   // A: m=query, k=key
        short8 vf = *(const short8*)&Vh[ch * 32 + quad * 8];    // B: n=dh,    k=key
        O = __builtin_amdgcn_mfma_f32_16x16x32_bf16(pf, vf, O, 0, 0, 0);
    }

    l += __shfl_xor(l, 16);
    l += __shfl_xor(l, 32);
    if (lane < 16)
        lpart[((size_t)h * N + qbase + q15) * NSPLIT + sp] = l;
#pragma unroll
    for (int r = 0; r < 4; ++r) {
        int query = qbase + quad * 4 + r;
        opart[(((size_t)h * N + query) * NSPLIT + sp) * 16 + q15] = O[r];
    }
}

// ===== D4b: combine splits -> Wc-weighted partial pool (no GEMMs, no atomics) =====
__global__ __launch_bounds__(256) void d4b_kernel(float* __restrict__ ws) {
    __shared__ float o_sh[16 * 68];
    __shared__ float Wc_sh[16][17];

    const float* opart = ws + OFF_OPART;
    const float* lpart = ws + OFF_LPART;
    const float* Wc    = ws + OFF_WC;   // [16][N]
    float*       Upart = ws + OFF_UPART;

    const int tid = threadIdx.x, qbase = blockIdx.x * 16;
    // combine: o_sh[r][f] = sum_s opart / sum_s lpart
    for (int idx = tid; idx < 16 * 64; idx += 256) {
        int r = idx >> 6, f = idx & 63;
        int h = f >> 4, d = f & 15;
        size_t base = ((size_t)h * N + qbase + r) * NSPLIT;
        float L = 0.f, acc = 0.f;
#pragma unroll
        for (int s = 0; s < NSPLIT; ++s) {
            L += lpart[base + s];
            acc += opart[(base + s) * 16 + d];
        }
        o_sh[r * 68 + f] = acc / L;
    }
    {
        int j = tid & 15, g = tid >> 4;   // contiguous 16-float reads per graph row
        Wc_sh[j][g] = Wc[(size_t)g * N + qbase + j];
    }
    __syncthreads();
    // Up[g][f] = sum_j Wc[g][qbase+j] * o[j][f]; thread = (g, f-quad)
    int g = tid >> 4, fq = tid & 15;
    float4 acc = {0.f, 0.f, 0.f, 0.f};
#pragma unroll
    for (int j = 0; j < 16; ++j) {
        float w = Wc_sh[j][g];
        const float* orow = &o_sh[j * 68 + fq * 4];
        acc.x += w * orow[0]; acc.y += w * orow[1];
        acc.z += w * orow[2]; acc.w += w * orow[3];
    }
    *(float4*)&Upart[(((size_t)blockIdx.x) * 16 + g) * 64 + fq * 4] = acc;
}

// ===== D6: reduce Upart -> U; s = rowsum(Wc); out = (U@Wout^T + s*b_out)@W2^T + b2 =====
__global__ __launch_bounds__(256) void d6_kernel(const float* __restrict__ Wout,
        const float* __restrict__ b_out, const float* __restrict__ W2,
        const float* __restrict__ b2, const float* __restrict__ ws,
        float* __restrict__ out) {
    __shared__ float red[4][64];
    __shared__ float s_red[4];
    __shared__ float U_sh[64], V_sh[64];

    const float* Upart = ws + OFF_UPART;
    const float* Wc    = ws + OFF_WC;    // [16][N]
    const float* invcnt= ws + OFF_INV;

    const int b = blockIdx.x, tid = threadIdx.x, lane = tid & 63, wv = tid >> 6;
    float acc = 0.f;
    for (int blk = wv; blk < 256; blk += 4)
        acc += Upart[((size_t)blk * 16 + b) * 64 + lane];
    red[wv][lane] = acc;
    float sacc = 0.f;
    for (int j = tid; j < N; j += 256) sacc += Wc[(size_t)b * N + j];
#pragma unroll
    for (int off = 1; off < 64; off <<= 1) sacc += __shfl_xor(sacc, off);
    if (lane == 0) s_red[wv] = sacc;
    __syncthreads();
    if (wv == 0)
        U_sh[lane] = (red[0][lane] + red[1][lane]) + (red[2][lane] + red[3][lane]);
    __syncthreads();
    const float s = (s_red[0] + s_red[1]) + (s_red[2] + s_red[3]);
    if (tid < 64) {
        float v = s * b_out[tid];
#pragma unroll 8
        for (int k = 0; k < 64; ++k) v += U_sh[k] * Wout[tid * 64 + k];
        V_sh[tid] = v;
    }
    __syncthreads();
    if (tid < OUTF) {
        float o = b2[tid];
#pragma unroll 8
        for (int f = 0; f < 64; ++f) o += V_sh[f] * W2[tid * 64 + f];
        out[b * OUTF + tid] = invcnt[b] > 0.f ? o : 0.0f;
    }
}

extern "C" void kernel_launch(void* const* d_in, const int* in_sizes, int n_in,
                              void* d_out, int out_size, void* d_ws, size_t ws_size,
                              hipStream_t stream) {
    const float* x     = (const float*)d_in[0];
    const int*   ei    = (const int*)  d_in[1];
    const float* ea    = (const float*)d_in[2];
    const int*   batch = (const int*)  d_in[3];
    const float* W1    = (const float*)d_in[4];
    const float* b1    = (const float*)d_in[5];
    const float* Win   = (const float*)d_in[6];
    const float* b_in  = (const float*)d_in[7];
    const float* Wout  = (const float*)d_in[8];
    const float* b_out = (const float*)d_in[9];
    const float* W2    = (const float*)d_in[10];
    const float* b2    = (const float*)d_in[11];
    float* out = (float*)d_out;
    float* ws  = (float*)d_ws;

    // zero pck (16N) + Wc (16N) in one contiguous memset (512 KB)
    hipMemsetAsync(ws + OFF_PCK, 0, (size_t)32 * N * 4, stream);
    d1_kernel<<<513, 256, 0, stream>>>(x, W1, ei, ea, batch, ws);
    d23_kernel<<<N / 16, 1024, 0, stream>>>(Win, b1, b_in, batch, ws);
    attn_kernel<<<dim3(N / 64, HEADS, NSPLIT), 256, 0, stream>>>(ws, ws);
    d4b_kernel<<<N / 16, 256, 0, stream>>>(ws);
    d6_kernel<<<NB, 256, 0, stream>>>(Wout, b_out, W2, b2, ws, out);
}

// Round 14
// 154.859 us; speedup vs baseline: 1.0701x; 1.0697x over previous
//
#include <hip/hip_runtime.h>

// Problem constants
constexpr int N = 4096, E = 131072, OUTF = 86, NB = 16, HEADS = 4, DH = 16;
constexpr int CAP = 128;   // padded bucket capacity per node (mean deg = 32)
constexpr int NSPLIT = 8, KEYS = N / NSPLIT;  // 512 keys per attention split
constexpr int PCKS = 8;    // u64 stride per node in pck (64 B line per node)

typedef __attribute__((ext_vector_type(8))) short short8;
typedef __attribute__((ext_vector_type(4))) float f32x4;

constexpr unsigned long long PK_MASK = (1ULL << 40) - 1;  // low 40: fixed-point deg
constexpr float PK_SCALE = 1.0f / 16777216.0f;            // 2^-24

// Workspace offsets (float units, 16B-aligned)
constexpr size_t OFF_PCK   = 0;                           // N*PCKS u64 = 16N words
constexpr size_t OFF_INV   = OFF_PCK + 16 * (size_t)N;    // 16
constexpr size_t OFF_BUFA  = OFF_INV + 16;                // N*64 (xW1)
constexpr size_t OFF_QP    = OFF_BUFA + (size_t)N * 64;   // HEADS*N*16 bf16 = N*32 floats
constexpr size_t OFF_KP    = OFF_QP + (size_t)N * 32;
constexpr size_t OFF_VP    = OFF_KP + (size_t)N * 32;     // [h][16][N] bf16
constexpr size_t OFF_H2    = OFF_VP + (size_t)N * 32;     // N*86 (h2pre)
constexpr size_t OFF_EPAIR = OFF_H2 + (size_t)N * 86;     // N*CAP int2 {src, w}
constexpr size_t OFF_NORMV = OFF_EPAIR + (size_t)2 * N * CAP;  // N*CAP floats
constexpr size_t OFF_OPART = OFF_NORMV + (size_t)N * CAP; // HEADS*N*NSPLIT*16
constexpr size_t OFF_LPART = OFF_OPART + (size_t)HEADS * N * NSPLIT * 16;  // HEADS*N*NSPLIT

__device__ inline unsigned short f2bf(float f) {  // RNE float->bf16
    unsigned u = __builtin_bit_cast(unsigned, f);
    u += 0x7FFFu + ((u >> 16) & 1u);
    return (unsigned short)(u >> 16);
}

__device__ inline float pk_deg(unsigned long long pk) {   // decode weighted degree
    return (float)(pk & PK_MASK) * PK_SCALE;
}

// ===== D1: gemm1 (blk<256) || edge bucket fill x2 (256..511) || out-init (512) =====
__global__ __launch_bounds__(256) void d1_kernel(const float* __restrict__ x,
        const float* __restrict__ W1, const int* __restrict__ ei,
        const float* __restrict__ ea, const int* __restrict__ batch,
        const float* __restrict__ b2, float* __restrict__ ws, float* __restrict__ out) {
    __shared__ float4 Ws4[64 * 17];
    __shared__ float4 As4[16 * 17];
    __shared__ int bnd[NB + 1];
    int blk = blockIdx.x, tid = threadIdx.x;
    if (blk < 256) {
        float* bufA = ws + OFF_BUFA;
        for (int idx = tid; idx < 64 * 16; idx += 256)
            Ws4[(idx >> 4) * 17 + (idx & 15)] = ((const float4*)W1)[idx];
        {
            int r = tid >> 4, k4 = tid & 15;
            As4[r * 17 + k4] = ((const float4*)x)[(size_t)(blk * 16 + r) * 16 + k4];
        }
        __syncthreads();
        int r2 = tid & 7, cg = tid >> 3;
        float acc[2][2] = {};
#pragma unroll
        for (int k4 = 0; k4 < 16; ++k4) {
            float4 a0 = As4[r2 * 17 + k4], a1 = As4[(r2 + 8) * 17 + k4];
#pragma unroll
            for (int i = 0; i < 2; ++i) {
                float4 w = Ws4[(cg + 32 * i) * 17 + k4];
                acc[0][i] += a0.x * w.x + a0.y * w.y + a0.z * w.z + a0.w * w.w;
                acc[1][i] += a1.x * w.x + a1.y * w.y + a1.z * w.z + a1.w * w.w;
            }
        }
#pragma unroll
        for (int j = 0; j < 2; ++j)
#pragma unroll
            for (int i = 0; i < 2; ++i)
                bufA[(size_t)(blk * 16 + r2 + 8 * j) * 64 + cg + 32 * i] = acc[j][i];
    } else if (blk < 512) {
        unsigned long long* pck = (unsigned long long*)(ws + OFF_PCK);
        int2* epair = (int2*)(ws + OFF_EPAIR);
        int f = (blk - 256) * 256 + tid;          // [0, E/2)
        int e0 = f, e1 = f + E / 2;
        int s0 = ei[e0], d0 = ei[E + e0];
        int s1 = ei[e1], d1 = ei[E + e1];
        float w0 = ea[e0], w1 = ea[e1];
        unsigned long long a0 = (1ULL << 40) + (unsigned long long)(unsigned)(w0 * 16777216.0f + 0.5f);
        unsigned long long a1 = (1ULL << 40) + (unsigned long long)(unsigned)(w1 * 16777216.0f + 0.5f);
        unsigned long long o0 = atomicAdd(&pck[(size_t)d0 * PCKS], a0);
        unsigned long long o1 = atomicAdd(&pck[(size_t)d1 * PCKS], a1);
        int p0 = (int)(o0 >> 40), p1 = (int)(o1 >> 40);
        if (p0 < CAP) epair[(size_t)d0 * CAP + p0] = make_int2(s0, __float_as_int(w0));
        if (p1 < CAP) epair[(size_t)d1 * CAP + p1] = make_int2(s1, __float_as_int(w1));
    } else {
        // out-init: 17 PARALLEL binary searches (one per graph boundary), then broadcast
        float* invcnt = ws + OFF_INV;
        if (tid <= NB) {
            int b = tid, lo = 0, hi = N;
            while (lo < hi) { int m = (lo + hi) >> 1; if (batch[m] < b) lo = m + 1; else hi = m; }
            bnd[tid] = lo;
        }
        __syncthreads();
        if (tid < NB) {
            int cnt = bnd[tid + 1] - bnd[tid];
            invcnt[tid] = cnt > 0 ? 1.0f / (float)cnt : 0.0f;
        }
        for (int idx = tid; idx < NB * OUTF; idx += 256) {
            int b = idx / OUTF;
            int cnt = bnd[b + 1] - bnd[b];
            out[idx] = cnt > 0 ? b2[idx - b * OUTF] : 0.0f;
        }
    }
}

// ===== D23: fused agg1(+b1,ReLU in LDS) -> QKV gemm + bf16 pack =====
// block = 1024 threads = 16 waves = 16 nodes. Phase 1: per-wave lane-batched gather.
// Phase 2: wave r computes QKV row r from LDS h1 (64 lanes x 3 cols).
__global__ __launch_bounds__(1024) void d23_kernel(const float* __restrict__ Win,
        const float* __restrict__ b1, const float* __restrict__ b_in,
        float* __restrict__ ws) {
    __shared__ float4 Ws4[16 * 200];   // [k4][c] (c<192, pad 200): reads lane-consecutive
    __shared__ float  Af[16 * 68];     // h1 rows (stride 68 floats = 17 float4)

    const unsigned long long* pck = (const unsigned long long*)(ws + OFF_PCK);
    const int2*  epair = (const int2*)(ws + OFF_EPAIR);
    float*       normv = ws + OFF_NORMV;
    const float* bufA  = ws + OFF_BUFA;
    unsigned short* Qp = (unsigned short*)(ws + OFF_QP);
    unsigned short* Kp = (unsigned short*)(ws + OFF_KP);
    unsigned short* Vp = (unsigned short*)(ws + OFF_VP);

    const int tid = threadIdx.x, lane = tid & 63, wv = tid >> 6;
    for (int idx = tid; idx < 192 * 16; idx += 1024) {
        int c = idx >> 4, k4 = idx & 15;
        Ws4[k4 * 200 + c] = ((const float4*)Win)[idx];
    }

    // phase 1: wave wv aggregates node
    const int node = blockIdx.x * 16 + wv;
    {
        const unsigned long long pkn = pck[(size_t)node * PCKS];
        const float di = rsqrtf(pk_deg(pkn) + 1.0f);   // self-loop: deg+1
        float acc0 = (di * di) * bufA[(size_t)node * 64 + lane];
        float acc1 = 0.f, acc2 = 0.f, acc3 = 0.f;
        const int cnt = min((int)(pkn >> 40), CAP);
        const int2* pe = epair + (size_t)node * CAP;
        for (int base = 0; base < cnt; base += 64) {
            int rem = cnt - base;
            int   sl = 0;
            float nl = 0.f;
            if (lane < rem) {                      // coalesced 8B load per lane
                int2 e = pe[base + lane];
                sl = e.x;
                float w = __int_as_float(e.y);
                nl = rsqrtf(pk_deg(pck[(size_t)sl * PCKS]) + 1.0f) * w * di;
                normv[(size_t)node * CAP + base + lane] = nl;   // for D5
            }
            int m = rem < 64 ? rem : 64;
            int j = 0;
            for (; j + 4 <= m; j += 4) {           // 4 row-gathers in flight
                int   s0 = __shfl(sl, j),     s1 = __shfl(sl, j + 1);
                int   s2 = __shfl(sl, j + 2), s3 = __shfl(sl, j + 3);
                float n0 = __shfl(nl, j),     n1 = __shfl(nl, j + 1);
                float n2 = __shfl(nl, j + 2), n3 = __shfl(nl, j + 3);
                acc0 += n0 * bufA[(size_t)s0 * 64 + lane];
                acc1 += n1 * bufA[(size_t)s1 * 64 + lane];
                acc2 += n2 * bufA[(size_t)s2 * 64 + lane];
                acc3 += n3 * bufA[(size_t)s3 * 64 + lane];
            }
            for (; j < m; ++j) {
                int   s0 = __shfl(sl, j);
                float n0 = __shfl(nl, j);
                acc0 += n0 * bufA[(size_t)s0 * 64 + lane];
            }
        }
        Af[wv * 68 + lane] = fmaxf((acc0 + acc1) + (acc2 + acc3) + b1[lane], 0.0f);
    }
    __syncthreads();

    // phase 2: wave wv computes QKV row (node); lane handles cols {lane, lane+64, lane+128}
    {
        const float4* Af4 = (const float4*)Af;
        float acc[3];
#pragma unroll
        for (int i = 0; i < 3; ++i) acc[i] = b_in[lane + 64 * i];
#pragma unroll
        for (int k4 = 0; k4 < 16; ++k4) {
            float4 a = Af4[wv * 17 + k4];          // wave-broadcast
#pragma unroll
            for (int i = 0; i < 3; ++i) {
                float4 w = Ws4[k4 * 200 + lane + 64 * i];  // lane-consecutive
                acc[i] += a.x * w.x + a.y * w.y + a.z * w.z + a.w * w.w;
            }
        }
        const int row = node;
#pragma unroll
        for (int i = 0; i < 3; ++i) {
            int c = lane + 64 * i;
            float v = acc[i];
            if (c < 64) {
                int h = c >> 4, d = c & 15;
                Qp[((size_t)h * N + row) * 16 + d] = f2bf(v * 0.25f);  // 1/sqrt(DH)
            } else if (c < 128) {
                int c2 = c - 64, h = c2 >> 4, d = c2 & 15;
                Kp[((size_t)h * N + row) * 16 + d] = f2bf(v);
            } else {
                int c2 = c - 128, h = c2 >> 4, d = c2 & 15;
                Vp[((size_t)h * 16 + d) * N + row] = f2bf(v);
            }
        }
    }
}

// ===== attn: MFMA flash attention, KV-split (proven) =====
__global__ __launch_bounds__(256) void attn_kernel(const float* __restrict__ ws_c,
        float* __restrict__ ws) {
    __shared__ __align__(16) unsigned short Plds[4 * 640];  // per-wave P roundtrip

    const unsigned short* Qp = (const unsigned short*)(ws_c + OFF_QP);
    const unsigned short* Kp = (const unsigned short*)(ws_c + OFF_KP);
    const unsigned short* Vp = (const unsigned short*)(ws_c + OFF_VP);
    float* opart = ws + OFF_OPART;
    float* lpart = ws + OFF_LPART;

    const int h  = blockIdx.y;
    const int sp = blockIdx.z;
    const int k0 = sp * KEYS;
    const int tid = threadIdx.x;
    const int lane = tid & 63, wv = tid >> 6;
    const int q15 = lane & 15, quad = lane >> 4;

    const int qbase = blockIdx.x * 64 + wv * 16;
    short8 qf = {};
    if (quad < 2)
        qf = *(const short8*)&Qp[((size_t)h * N + qbase + q15) * 16 + quad * 8];

    f32x4 O = {0.f, 0.f, 0.f, 0.f};
    float l = 0.f;
    unsigned short* Pw = &Plds[wv * 640];
    const unsigned short* Kh = Kp + (size_t)h * N * 16;
    const unsigned short* Vh = Vp + ((size_t)h * 16 + q15) * N + k0;

#pragma unroll 2
    for (int ch = 0; ch < KEYS / 32; ++ch) {
#pragma unroll
        for (int t = 0; t < 2; ++t) {
            short8 kf = {};
            if (quad < 2)
                kf = *(const short8*)&Kh[(size_t)(k0 + ch * 32 + t * 16 + q15) * 16 + quad * 8];
            f32x4 zero = {0.f, 0.f, 0.f, 0.f};
            f32x4 s = __builtin_amdgcn_mfma_f32_16x16x32_bf16(kf, qf, zero, 0, 0, 0);
            // C-layout: col=query=lane&15, row=key=quad*4+reg
            float p0 = __expf(s[0]), p1 = __expf(s[1]), p2 = __expf(s[2]), p3 = __expf(s[3]);
            l += p0 + p1 + p2 + p3;
            ushort4 pu;
            pu.x = f2bf(p0); pu.y = f2bf(p1); pu.z = f2bf(p2); pu.w = f2bf(p3);
            *(ushort4*)&Pw[q15 * 40 + t * 16 + quad * 4] = pu;
        }
        asm volatile("s_waitcnt lgkmcnt(0)" ::: "memory");
        short8 pf = *(const short8*)&Pw[q15 * 40 + quad * 8];   // A: m=query, k=key
        short8 vf = *(const short8*)&Vh[ch * 32 + quad * 8];    // B: n=dh,    k=key
        O = __builtin_amdgcn_mfma_f32_16x16x32_bf16(pf, vf, O, 0, 0, 0);
    }

    l += __shfl_xor(l, 16);
    l += __shfl_xor(l, 32);
    if (lane < 16)
        lpart[((size_t)h * N + qbase + q15) * NSPLIT + sp] = l;
#pragma unroll
    for (int r = 0; r < 4; ++r) {
        int query = qbase + quad * 4 + r;
        opart[(((size_t)h * N + query) * NSPLIT + sp) * 16 + q15] = O[r];
    }
}

// ===== D4b: combine splits -> Wout gemm (+b_out) -> W2 gemm -> h2pre =====
__global__ __launch_bounds__(256) void d4b_kernel(const float* __restrict__ Wout,
        const float* __restrict__ b_out, const float* __restrict__ W2,
        float* __restrict__ ws) {
    __shared__ float4 WoS[64 * 17];    // 17408
    __shared__ float4 W2S[96 * 17];    // 26112 (86 used)
    __shared__ float  o_sh[16 * 68];   // 4352
    __shared__ float  Bf[16 * 68];     // 4352

    const float* opart = ws + OFF_OPART;
    const float* lpart = ws + OFF_LPART;
    float* h2pre = ws + OFF_H2;

    const int tid = threadIdx.x, qbase = blockIdx.x * 16;
    for (int idx = tid; idx < 64 * 16; idx += 256)
        WoS[(idx >> 4) * 17 + (idx & 15)] = ((const float4*)Wout)[idx];
    for (int idx = tid; idx < 86 * 16; idx += 256)
        W2S[(idx >> 4) * 17 + (idx & 15)] = ((const float4*)W2)[idx];

    // combine: o_sh[r][f] = sum_s opart / sum_s lpart
    for (int idx = tid; idx < 16 * 64; idx += 256) {
        int r = idx >> 6, f = idx & 63;
        int h = f >> 4, d = f & 15;
        size_t base = ((size_t)h * N + qbase + r) * NSPLIT;
        float L = 0.f, acc = 0.f;
#pragma unroll
        for (int s = 0; s < NSPLIT; ++s) {
            L += lpart[base + s];
            acc += opart[(base + s) * 16 + d];
        }
        o_sh[r * 68 + f] = acc / L;
    }
    __syncthreads();
    // Wout gemm: 16 rows x 64 cols
    {
        int r = tid & 15, c0 = tid >> 4;
        float4* o4 = (float4*)o_sh;
#pragma unroll
        for (int i = 0; i < 4; ++i) {
            int c = c0 + 16 * i;
            float acc = b_out[c];
#pragma unroll
            for (int k4 = 0; k4 < 16; ++k4) {
                float4 a = o4[r * 17 + k4];
                float4 w = WoS[c * 17 + k4];
                acc += a.x * w.x + a.y * w.y + a.z * w.z + a.w * w.w;
            }
            Bf[r * 68 + c] = acc;
        }
    }
    __syncthreads();
    // W2 gemm: 16 rows x 86 cols -> h2pre
    {
        int r = tid & 15, c0 = tid >> 4;
        float4* B4 = (float4*)Bf;
#pragma unroll
        for (int i = 0; i < 6; ++i) {
            int c = c0 + 16 * i;
            if (c < OUTF) {
                float acc = 0.f;
#pragma unroll
                for (int k4 = 0; k4 < 16; ++k4) {
                    float4 a = B4[r * 17 + k4];
                    float4 w = W2S[c * 17 + k4];
                    acc += a.x * w.x + a.y * w.y + a.z * w.z + a.w * w.w;
                }
                h2pre[(size_t)(qbase + r) * OUTF + c] = acc;
            }
        }
    }
}

// ===== D5: agg2 + LDS per-graph pre-reduction + few atomics into out =====
__global__ __launch_bounds__(1024) void d5_kernel(const int* __restrict__ batch,
        float* __restrict__ ws, float* __restrict__ out) {
    __shared__ float vec[16][88];
    __shared__ int   bix[16];

    const unsigned long long* pck = (const unsigned long long*)(ws + OFF_PCK);
    const int2*  epair = (const int2*)(ws + OFF_EPAIR);
    const float* normv = ws + OFF_NORMV;   // norms (written by D23)
    const float* invcnt= ws + OFF_INV;
    const float* h2pre = ws + OFF_H2;

    const int tid = threadIdx.x;
    const int lane = tid & 63, wv = tid >> 6;        // wv in [0,16)
    const int node = blockIdx.x * 16 + wv;
    const bool hi2 = lane < (OUTF - 64);
    const int b = batch[node];
    const float inv = invcnt[b];
    const unsigned long long pkn = pck[(size_t)node * PCKS];
    const float di2 = 1.0f / (pk_deg(pkn) + 1.0f);
    const float* Hn = h2pre + (size_t)node * OUTF;
    float a0 = di2 * Hn[lane],                  a1 = 0.f, a2 = 0.f, a3 = 0.f;
    float c0 = hi2 ? di2 * Hn[64 + lane] : 0.f, c1 = 0.f, c2 = 0.f, c3 = 0.f;
    const int cnt = min((int)(pkn >> 40), CAP);
    const int2* pe = epair + (size_t)node * CAP;

    for (int base = 0; base < cnt; base += 64) {
        int rem = cnt - base;
        int   sl = 0;
        float nl = 0.f;
        if (lane < rem) {
            sl = pe[base + lane].x;
            nl = normv[(size_t)node * CAP + base + lane];
        }
        int m = rem < 64 ? rem : 64;
        int j = 0;
        for (; j + 4 <= m; j += 4) {
            int   s0 = __shfl(sl, j),     s1 = __shfl(sl, j + 1);
            int   s2 = __shfl(sl, j + 2), s3 = __shfl(sl, j + 3);
            float n0 = __shfl(nl, j),     n1 = __shfl(nl, j + 1);
            float n2 = __shfl(nl, j + 2), n3 = __shfl(nl, j + 3);
            const float* H0 = h2pre + (size_t)s0 * OUTF;
            const float* H1 = h2pre + (size_t)s1 * OUTF;
            const float* H2 = h2pre + (size_t)s2 * OUTF;
            const float* H3 = h2pre + (size_t)s3 * OUTF;
            a0 += n0 * H0[lane]; if (hi2) c0 += n0 * H0[64 + lane];
            a1 += n1 * H1[lane]; if (hi2) c1 += n1 * H1[64 + lane];
            a2 += n2 * H2[lane]; if (hi2) c2 += n2 * H2[64 + lane];
            a3 += n3 * H3[lane]; if (hi2) c3 += n3 * H3[64 + lane];
        }
        for (; j < m; ++j) {
            int   s0 = __shfl(sl, j);
            float n0 = __shfl(nl, j);
            const float* H0 = h2pre + (size_t)s0 * OUTF;
            a0 += n0 * H0[lane];
            if (hi2) c0 += n0 * H0[64 + lane];
        }
    }
    vec[wv][lane] = ((a0 + a1) + (a2 + a3)) * inv;
    if (hi2) vec[wv][64 + lane] = ((c0 + c1) + (c2 + c3)) * inv;
    if (lane == 0) bix[wv] = b;
    __syncthreads();
    // per-graph pre-reduction over the 16 sorted nodes: 1 atomic per (graph, feat) per block
    if (tid < OUTF) {
        int curb = bix[0];
        float acc = 0.f;
#pragma unroll
        for (int w = 0; w < 16; ++w) {
            int bw = bix[w];
            if (bw != curb) {
                atomicAdd(&out[curb * OUTF + tid], acc);
                curb = bw; acc = 0.f;
            }
            acc += vec[w][tid];
        }
        atomicAdd(&out[curb * OUTF + tid], acc);
    }
}

extern "C" void kernel_launch(void* const* d_in, const int* in_sizes, int n_in,
                              void* d_out, int out_size, void* d_ws, size_t ws_size,
                              hipStream_t stream) {
    const float* x     = (const float*)d_in[0];
    const int*   ei    = (const int*)  d_in[1];
    const float* ea    = (const float*)d_in[2];
    const int*   batch = (const int*)  d_in[3];
    const float* W1    = (const float*)d_in[4];
    const float* b1    = (const float*)d_in[5];
    const float* Win   = (const float*)d_in[6];
    const float* b_in  = (const float*)d_in[7];
    const float* Wout  = (const float*)d_in[8];
    const float* b_out = (const float*)d_in[9];
    const float* W2    = (const float*)d_in[10];
    const float* b2    = (const float*)d_in[11];
    float* out = (float*)d_out;
    float* ws  = (float*)d_ws;

    // zero padded pck array (N lines of 64 B)
    hipMemsetAsync(ws + OFF_PCK, 0, (size_t)N * 64, stream);
    d1_kernel<<<513, 256, 0, stream>>>(x, W1, ei, ea, batch, b2, ws, out);
    d23_kernel<<<N / 16, 1024, 0, stream>>>(Win, b1, b_in, ws);
    attn_kernel<<<dim3(N / 64, HEADS, NSPLIT), 256, 0, stream>>>(ws, ws);
    d4b_kernel<<<N / 16, 256, 0, stream>>>(Wout, b_out, W2, ws);
    d5_kernel<<<N / 16, 1024, 0, stream>>>(batch, ws, out);
}